// Round 1
// baseline (88.511 us; speedup 1.0000x reference)
//
#include <hip/hip_runtime.h>

// TemperatureScaler: piecewise-linear temperature scaling of logits.
// out = T[bin]*(x - thr_pad[bin]) + c_pad[bin],  bin = #{sorted_thr < x}
// B=64, V=128000 -> 8,192,000 fp32 elements. Memory-bound streaming kernel.

#define PIECES 8
#define NTHR (PIECES - 1)
#define TEMP_CLAMP_MIN 1e-4f

__global__ __launch_bounds__(256) void temp_scale_kernel(
    const float4* __restrict__ x4,
    float4* __restrict__ out4,
    const float* __restrict__ temperature,   // (PIECES,)
    const float* __restrict__ thresholds,    // (NTHR,)
    int n4, int n_tail, const float* __restrict__ x_tail_base,
    float* __restrict__ out_tail_base)
{
    // --- per-block param prep in LDS (thread 0; trivial redundant work,
    //     saves a second kernel launch which matters at a ~10us floor) ---
    __shared__ float sT[PIECES];    // clamped temperatures
    __shared__ float sTP[PIECES];   // thr_pad: [0, thr_sorted...]
    __shared__ float sCP[PIECES];   // c_pad:   [0, cumsum continuity...]

    if (threadIdx.x == 0) {
        float T[PIECES], thr[NTHR];
        #pragma unroll
        for (int j = 0; j < PIECES; ++j) T[j] = fmaxf(temperature[j], TEMP_CLAMP_MIN);
        #pragma unroll
        for (int j = 0; j < NTHR; ++j) thr[j] = thresholds[j];
        // insertion sort (7 elements; input is linspace-sorted, but match ref's jnp.sort)
        for (int i = 1; i < NTHR; ++i) {
            float key = thr[i];
            int j = i - 1;
            while (j >= 0 && thr[j] > key) { thr[j + 1] = thr[j]; --j; }
            thr[j + 1] = key;
        }
        // continuity constants: c = cumsum(diff(pad(thr,left 0)) * T[:-1])
        float prev = 0.f, acc = 0.f;
        sTP[0] = 0.f; sCP[0] = 0.f;
        for (int k = 0; k < NTHR; ++k) {
            acc += (thr[k] - prev) * T[k];
            prev = thr[k];
            sTP[k + 1] = thr[k];
            sCP[k + 1] = acc;
        }
        #pragma unroll
        for (int j = 0; j < PIECES; ++j) sT[j] = T[j];
    }
    __syncthreads();

    // params to registers (wave-uniform values; select cascade below keeps
    // them as static indices -> no scratch spill)
    float T[PIECES], tp[PIECES], cp[PIECES];
    #pragma unroll
    for (int j = 0; j < PIECES; ++j) { T[j] = sT[j]; tp[j] = sTP[j]; cp[j] = sCP[j]; }

    const int stride = gridDim.x * blockDim.x;
    int i = blockIdx.x * blockDim.x + threadIdx.x;

    for (; i < n4; i += stride) {
        float4 v = x4[i];
        float xs[4] = {v.x, v.y, v.z, v.w};
        float r[4];
        #pragma unroll
        for (int e = 0; e < 4; ++e) {
            float x = xs[e];
            // searchsorted side='left': bin = #{thr[j] < x}. tp is sorted
            // ascending, so (x > tp[j]) is a monotone prefix predicate;
            // the last true j selects the bin's affine params.
            float t = T[0], a = 0.f, c = 0.f;
            #pragma unroll
            for (int j = 1; j < PIECES; ++j) {
                bool gt = x > tp[j];
                t = gt ? T[j] : t;
                a = gt ? tp[j] : a;
                c = gt ? cp[j] : c;
            }
            r[e] = fmaf(t, x - a, c);
        }
        out4[i] = make_float4(r[0], r[1], r[2], r[3]);
    }

    // tail (n % 4 != 0) — not hit for 8,192,000 but kept for safety
    int gid = blockIdx.x * blockDim.x + threadIdx.x;
    if (gid < n_tail) {
        float x = x_tail_base[gid];
        float t = T[0], a = 0.f, c = 0.f;
        #pragma unroll
        for (int j = 1; j < PIECES; ++j) {
            bool gt = x > tp[j];
            t = gt ? T[j] : t;
            a = gt ? tp[j] : a;
            c = gt ? cp[j] : c;
        }
        out_tail_base[gid] = fmaf(t, x - a, c);
    }
}

extern "C" void kernel_launch(void* const* d_in, const int* in_sizes, int n_in,
                              void* d_out, int out_size, void* d_ws, size_t ws_size,
                              hipStream_t stream) {
    const float* logits      = (const float*)d_in[0];   // (B, V) fp32
    const float* temperature = (const float*)d_in[1];   // (1, PIECES) fp32
    const float* thresholds  = (const float*)d_in[2];   // (1, NTHR) fp32
    float* out = (float*)d_out;

    const int n = in_sizes[0];
    const int n4 = n / 4;
    const int n_tail = n - n4 * 4;

    const int block = 256;
    int grid = (n4 + block - 1) / block;   // 8000 blocks for 2,048,000 float4
    if (grid < 1) grid = 1;

    temp_scale_kernel<<<grid, block, 0, stream>>>(
        (const float4*)logits, (float4*)out, temperature, thresholds,
        n4, n_tail, logits + (size_t)n4 * 4, out + (size_t)n4 * 4);
}

// Round 2
// 86.893 us; speedup vs baseline: 1.0186x; 1.0186x over previous
//
#include <hip/hip_runtime.h>

// TemperatureScaler: piecewise-linear temperature scaling of logits.
// out = T[bin]*(x - thr_pad[bin]) + c_pad[bin],  bin = #{sorted_thr < x}
// B=64, V=128000 -> 8,192,000 fp32 elements. Pure streaming, memory-bound.
//
// R2 design: no LDS/barrier (params are uniform -> computed redundantly per
// thread with a branch-free sort, overlapping with the first data loads);
// 2000 blocks x 256 thr, each thread streams exactly 4 float4s (4-deep load
// batch for MLP). Prior barrier+1-iter/block structure spent ~40% of each
// block's life stalled on thread0's dependent prep chain.

#define PIECES 8
#define NTHR (PIECES - 1)
#define TEMP_CLAMP_MIN 1e-4f

struct Params {
    float T[PIECES];   // clamped temperatures
    float tp[PIECES];  // thr_pad: [0, thr_sorted...]
    float cp[PIECES];  // c_pad:   [0, continuity cumsum...]
};

__device__ __forceinline__ Params make_params(const float* __restrict__ temperature,
                                              const float* __restrict__ thresholds) {
    Params P;
    float thr[NTHR];
    #pragma unroll
    for (int j = 0; j < PIECES; ++j) P.T[j] = fmaxf(temperature[j], TEMP_CLAMP_MIN);
    #pragma unroll
    for (int j = 0; j < NTHR; ++j) thr[j] = thresholds[j];
    // branch-free bubble sort, 21 compare-exchanges (matches jnp.sort; the
    // actual input is linspace-sorted so this is an identity, but cheap)
    #pragma unroll
    for (int i = 0; i < NTHR - 1; ++i) {
        #pragma unroll
        for (int j = 0; j < NTHR - 1 - i; ++j) {
            float lo = fminf(thr[j], thr[j + 1]);
            float hi = fmaxf(thr[j], thr[j + 1]);
            thr[j] = lo; thr[j + 1] = hi;
        }
    }
    // continuity constants: c = cumsum(diff(pad(thr,left 0)) * T[:-1])
    float prev = 0.f, acc = 0.f;
    P.tp[0] = 0.f; P.cp[0] = 0.f;
    #pragma unroll
    for (int k = 0; k < NTHR; ++k) {
        acc += (thr[k] - prev) * P.T[k];
        prev = thr[k];
        P.tp[k + 1] = thr[k];
        P.cp[k + 1] = acc;
    }
    return P;
}

__device__ __forceinline__ float apply1(const Params& P, float x) {
    // searchsorted side='left': bin = #{thr < x}. tp sorted ascending ->
    // (x > tp[j]) is a monotone prefix predicate; last true j wins.
    float t = P.T[0], a = 0.f, c = 0.f;
    #pragma unroll
    for (int j = 1; j < PIECES; ++j) {
        bool gt = x > P.tp[j];
        t = gt ? P.T[j] : t;
        a = gt ? P.tp[j] : a;
        c = gt ? P.cp[j] : c;
    }
    return fmaf(t, x - a, c);
}

__device__ __forceinline__ float4 apply4(const Params& P, float4 v) {
    return make_float4(apply1(P, v.x), apply1(P, v.y), apply1(P, v.z), apply1(P, v.w));
}

__global__ __launch_bounds__(256) void temp_scale_kernel(
    const float4* __restrict__ x4,
    float4* __restrict__ out4,
    const float* __restrict__ temperature,
    const float* __restrict__ thresholds,
    int n4, int n_tail, const float* __restrict__ x_tail_base,
    float* __restrict__ out_tail_base)
{
    const Params P = make_params(temperature, thresholds);

    const int stride = gridDim.x * blockDim.x;
    const int tid = blockIdx.x * blockDim.x + threadIdx.x;

    int i = tid;
    // 4-deep batched main loop: 4 independent 16B loads in flight per thread
    for (; i + 3 * stride < n4; i += 4 * stride) {
        float4 a = x4[i];
        float4 b = x4[i + stride];
        float4 c = x4[i + 2 * stride];
        float4 d = x4[i + 3 * stride];
        out4[i]              = apply4(P, a);
        out4[i + stride]     = apply4(P, b);
        out4[i + 2 * stride] = apply4(P, c);
        out4[i + 3 * stride] = apply4(P, d);
    }
    for (; i < n4; i += stride) out4[i] = apply4(P, x4[i]);

    // scalar tail (n % 4) — empty for 8,192,000 but kept for safety
    if (tid < n_tail) out_tail_base[tid] = apply1(P, x_tail_base[tid]);
}

extern "C" void kernel_launch(void* const* d_in, const int* in_sizes, int n_in,
                              void* d_out, int out_size, void* d_ws, size_t ws_size,
                              hipStream_t stream) {
    const float* logits      = (const float*)d_in[0];   // (B, V) fp32
    const float* temperature = (const float*)d_in[1];   // (1, PIECES) fp32
    const float* thresholds  = (const float*)d_in[2];   // (1, NTHR) fp32
    float* out = (float*)d_out;

    const int n = in_sizes[0];
    const int n4 = n / 4;
    const int n_tail = n - n4 * 4;

    // 2000 blocks x 256 thr = 512,000 threads; n4 = 2,048,000 -> exactly 4
    // float4 per thread. ~7.8 blocks/CU, full occupancy at this VGPR count.
    const int block = 256;
    int grid = 2000;
    // keep the kernel generic for other sizes
    int need = (n4 + block - 1) / block;
    if (need < grid) grid = need;
    if (grid < 1) grid = 1;

    temp_scale_kernel<<<grid, block, 0, stream>>>(
        (const float4*)logits, (float4*)out, temperature, thresholds,
        n4, n_tail, logits + (size_t)n4 * 4, out + (size_t)n4 * 4);
}